// Round 2
// baseline (857.917 us; speedup 1.0000x reference)
//
#include <hip/hip_runtime.h>

// SelfAttention: B=4, L=4096, H=256, fp32 in/out.
// Round 2: barrier-free flash attention. K/V fragments are read directly from
// global (L1/L2-hot; per-batch K+V working set = 6 MB, LLC-resident) instead of
// LDS staging, eliminating both per-iteration __syncthreads. Split-K 2-way
// (waves 0,1 = keys [0,2048), waves 2,3 = [2048,4096)) doubles resident blocks
// to 2/CU = 8 waves/CU; merge once at the end via LDS. The only in-loop LDS use
// is the per-wave P C-layout -> A-layout round-trip (no cross-wave sync needed).
// Precision: split-bf16 3-product QK (fp32-accurate logits; logits O(1e4) with
// near-tie rows), plain-bf16 PV. Round-1 measured absmax 0.25 vs threshold 1.01.

typedef __bf16 bf16x8 __attribute__((ext_vector_type(8)));
typedef __bf16 bf16x4 __attribute__((ext_vector_type(4)));
typedef float floatx4 __attribute__((ext_vector_type(4)));

#define MFMA16(a, b, c) __builtin_amdgcn_mfma_f32_16x16x32_bf16(a, b, c, 0, 0, 0)

#define HID 256
#define LSEQ 4096
#define NB 4
#define NTOK (NB * LSEQ)             // 16384
#define QSCALE 0.09016844005556021f  // log2(e)/16 ; folded into Q so softmax uses exp2

__device__ __forceinline__ void split_bf16(float v, __bf16 &h, __bf16 &l) {
  h = (__bf16)v;
  l = (__bf16)(v - (float)h);
}

// ---------------------------------------------------------------------------
// Kernel 1: transpose + hi/lo-split the three weight matrices.
// Output: Wht/Wlt[w][n][h] (n-major) so GEMM B-fragments are 16B-contiguous.
// ---------------------------------------------------------------------------
__global__ __launch_bounds__(256) void wsplit(const float *__restrict__ Wq,
                                              const float *__restrict__ Wk,
                                              const float *__restrict__ Wv,
                                              __bf16 *__restrict__ Wht,
                                              __bf16 *__restrict__ Wlt) {
  __shared__ float tile[32][256];  // 32 KB
  const int wsel = blockIdx.x;
  const float *W = (wsel == 0) ? Wq : (wsel == 1) ? Wk : Wv;
  __bf16 *oh = Wht + wsel * HID * HID;
  __bf16 *ol = Wlt + wsel * HID * HID;
  const int t = threadIdx.x;
  for (int hb = 0; hb < 8; ++hb) {  // 32 h-rows per pass
    __syncthreads();
    #pragma unroll
    for (int p = 0; p < 8; ++p) {
      int r = p * 4 + (t >> 6);
      int c = (t & 63) * 4;
      *(floatx4 *)&tile[r][c] = *(const floatx4 *)&W[(hb * 32 + r) * HID + c];
    }
    __syncthreads();
    #pragma unroll
    for (int q = 0; q < 4; ++q) {
      int n = q * 64 + (t >> 2);
      int hs = (t & 3) * 8;
      bf16x8 hh, ll;
      #pragma unroll
      for (int i = 0; i < 8; ++i) {
        float v = tile[hs + i][n];
        __bf16 h, l;
        split_bf16(v, h, l);
        hh[i] = h; ll[i] = l;
      }
      *(bf16x8 *)&oh[n * HID + hb * 32 + hs] = hh;
      *(bf16x8 *)&ol[n * HID + hb * 32 + hs] = ll;
    }
  }
}

// ---------------------------------------------------------------------------
// Kernel 2: QKV projection, LDS-free MFMA GEMM. All three W's per block
// (A-frags built once -> X read 4x total instead of 12x).
// grid = (256 m-tiles of 64 tokens, 4 n-tiles of 64 cols).
// ---------------------------------------------------------------------------
__global__ __launch_bounds__(256) void qkv_proj(const float *__restrict__ X,
                                                const __bf16 *__restrict__ Wht,
                                                const __bf16 *__restrict__ Wlt,
                                                __bf16 *__restrict__ Qh, __bf16 *__restrict__ Ql,
                                                __bf16 *__restrict__ Kh, __bf16 *__restrict__ Kl,
                                                __bf16 *__restrict__ Vt) {
  const int mtile = blockIdx.x;        // 0..255
  const int col0 = blockIdx.y * 64;    // 0..3 -> col tile
  const int tid = threadIdx.x;
  const int w4 = tid >> 6;
  const int lane = tid & 63;
  const int quad = lane >> 4;
  const int ln = lane & 15;
  const int arow = mtile * 64 + w4 * 16 + ln;

  floatx4 acc[3][4] = {};
  #pragma unroll
  for (int kc = 0; kc < 8; ++kc) {
    const int koff = kc * 32 + quad * 8;
    const float *xp = X + arow * HID + koff;
    floatx4 x0 = *(const floatx4 *)xp;
    floatx4 x1 = *(const floatx4 *)(xp + 4);
    bf16x8 ah, al;
    #pragma unroll
    for (int j = 0; j < 4; ++j) {
      __bf16 h, l;
      split_bf16(x0[j], h, l); ah[j] = h; al[j] = l;
      split_bf16(x1[j], h, l); ah[4 + j] = h; al[4 + j] = l;
    }
    #pragma unroll
    for (int w = 0; w < 3; ++w) {
      const __bf16 *wh = Wht + w * HID * HID;
      const __bf16 *wl = Wlt + w * HID * HID;
      #pragma unroll
      for (int nt = 0; nt < 4; ++nt) {
        const int woff = (col0 + nt * 16 + ln) * HID + koff;
        bf16x8 bh = *(const bf16x8 *)&wh[woff];
        bf16x8 bl = *(const bf16x8 *)&wl[woff];
        acc[w][nt] = MFMA16(ah, bh, acc[w][nt]);
        acc[w][nt] = MFMA16(ah, bl, acc[w][nt]);
        acc[w][nt] = MFMA16(al, bh, acc[w][nt]);
      }
    }
  }

  // Epilogues. C/D layout: col = lane&15, row = quad*4 + reg (HW-verified).
  // Q (w=0): scale + hi/lo split. K (w=1): hi/lo split. V (w=2): bf16 transposed.
  #pragma unroll
  for (int w = 0; w < 2; ++w) {
    __bf16 *H = (w == 0) ? Qh : Kh;
    __bf16 *L = (w == 0) ? Ql : Kl;
    const float sc = (w == 0) ? QSCALE : 1.0f;
    #pragma unroll
    for (int nt = 0; nt < 4; ++nt) {
      #pragma unroll
      for (int r = 0; r < 4; ++r) {
        float v = acc[w][nt][r] * sc;
        __bf16 h, l;
        split_bf16(v, h, l);
        const int orow = mtile * 64 + w4 * 16 + quad * 4 + r;
        const int ocol = col0 + nt * 16 + ln;
        H[orow * HID + ocol] = h;
        L[orow * HID + ocol] = l;
      }
    }
  }
  {
    const int bb = mtile >> 6;
    const int l0 = (mtile & 63) * 64 + w4 * 16 + quad * 4;
    #pragma unroll
    for (int nt = 0; nt < 4; ++nt) {
      const int d = col0 + nt * 16 + ln;
      bf16x4 pk;
      #pragma unroll
      for (int r = 0; r < 4; ++r) pk[r] = (__bf16)acc[2][nt][r];
      *(bf16x4 *)&Vt[(size_t)(bb * HID + d) * LSEQ + l0] = pk;
    }
  }
}

// ---------------------------------------------------------------------------
// Kernel 3: barrier-free flash attention with split-K.
// grid = 512 blocks (b = bx>>7, qt = bx&127 -> 32 q-rows), 256 threads.
// Wave w: qsub = w&1 (16 q-rows), ksplit = w>>1 (2048 keys, 64 iters of 32).
// K/V frags straight from global (wave pair sharing ksplit reads identical
// addresses -> L1 dedup). In-loop LDS: per-wave P round-trip only, no barriers.
// End: split-K merge via LDS (ML + Oacc), 3 barriers total per kernel.
// ---------------------------------------------------------------------------
__global__ __launch_bounds__(256, 2) void attn(const __bf16 *__restrict__ QhG,
                                               const __bf16 *__restrict__ QlG,
                                               const __bf16 *__restrict__ KhG,
                                               const __bf16 *__restrict__ KlG,
                                               const __bf16 *__restrict__ VtG,
                                               float *__restrict__ Out) {
  __shared__ __bf16 PsS[4 * 16 * 40];    // per-wave P round-trip, 5.1 KB
  __shared__ float Oacc[32 * 258];       // merge accumulator, 33 KB (padded stride)
  __shared__ float MLm[2][32], MLl[2][32];

  const int bx = blockIdx.x;
  const int b = bx >> 7;
  const int qt = bx & 127;
  const int tid = threadIdx.x;
  const int w4 = tid >> 6;
  const int qsub = w4 & 1;
  const int ksplit = w4 >> 1;
  const int lane = tid & 63;
  const int quad = lane >> 4;
  const int ln = lane & 15;

  // Preload Q fragments (hi+lo) for this wave's 16 q-rows.
  const int qtok = b * LSEQ + qt * 32 + qsub * 16 + ln;
  bf16x8 qh[8], ql[8];
  #pragma unroll
  for (int kc = 0; kc < 8; ++kc) {
    const int off = qtok * HID + kc * 32 + quad * 8;
    qh[kc] = *(const bf16x8 *)&QhG[off];
    ql[kc] = *(const bf16x8 *)&QlG[off];
  }

  // Per-wave global base offsets for K and V fragment streams.
  const size_t krow = (size_t)(b * LSEQ + ksplit * 2048 + ln) * HID + quad * 8;
  const size_t vrow = (size_t)(b * HID + ln) * LSEQ + ksplit * 2048 + quad * 8;
  __bf16 *ps = PsS + w4 * 16 * 40;

  float m[4] = {-1e30f, -1e30f, -1e30f, -1e30f};
  float l[4] = {0.f, 0.f, 0.f, 0.f};
  floatx4 o[16] = {};

  for (int kt = 0; kt < 64; ++kt) {
    const size_t kb = krow + (size_t)kt * 32 * HID;

    // ---- S = Q K^T (3-product split), K frags direct from global ----
    floatx4 s[2] = {};
    #pragma unroll
    for (int kc = 0; kc < 8; ++kc) {
      #pragma unroll
      for (int nt = 0; nt < 2; ++nt) {
        const size_t off = kb + nt * 16 * HID + kc * 32;
        bf16x8 bh = *(const bf16x8 *)&KhG[off];
        bf16x8 bl = *(const bf16x8 *)&KlG[off];
        s[nt] = MFMA16(qh[kc], bh, s[nt]);
        s[nt] = MFMA16(qh[kc], bl, s[nt]);
        s[nt] = MFMA16(ql[kc], bh, s[nt]);
      }
    }

    // ---- V frag prefetch (lands during softmax) ----
    bf16x8 vb[16];
    #pragma unroll
    for (int dt = 0; dt < 16; ++dt)
      vb[dt] = *(const bf16x8 *)&VtG[vrow + (size_t)dt * 16 * LSEQ + kt * 32];

    // ---- online softmax (base-2; log2e folded into Q) ----
    float alpha[4];
    #pragma unroll
    for (int r = 0; r < 4; ++r) {
      float tmax = fmaxf(s[0][r], s[1][r]);
      #pragma unroll
      for (int d = 1; d < 16; d <<= 1) tmax = fmaxf(tmax, __shfl_xor(tmax, d));
      const float mn = fmaxf(m[r], tmax);
      const float al = exp2f(m[r] - mn);
      const float p0 = exp2f(s[0][r] - mn);
      const float p1 = exp2f(s[1][r] - mn);
      s[0][r] = p0; s[1][r] = p1;
      float rs = p0 + p1;
      #pragma unroll
      for (int d = 1; d < 16; d <<= 1) rs += __shfl_xor(rs, d);
      l[r] = l[r] * al + rs;
      m[r] = mn;
      alpha[r] = al;
    }
    #pragma unroll
    for (int dt = 0; dt < 16; ++dt) {
      o[dt][0] *= alpha[0]; o[dt][1] *= alpha[1];
      o[dt][2] *= alpha[2]; o[dt][3] *= alpha[3];
    }

    // ---- P: C-layout regs -> per-wave LDS -> A-frag (same-wave, no barrier) ----
    #pragma unroll
    for (int nt = 0; nt < 2; ++nt)
      #pragma unroll
      for (int r = 0; r < 4; ++r)
        ps[(quad * 4 + r) * 40 + nt * 16 + ln] = (__bf16)s[nt][r];
    const bf16x8 pa = *(const bf16x8 *)&ps[ln * 40 + quad * 8];

    // ---- O += P V ----
    #pragma unroll
    for (int dt = 0; dt < 16; ++dt)
      o[dt] = MFMA16(pa, vb[dt], o[dt]);
  }

  // ---- split-K merge across the two ksplit wave-groups ----
  if (ln == 0) {
    #pragma unroll
    for (int r = 0; r < 4; ++r) {
      const int row = qsub * 16 + quad * 4 + r;
      MLm[ksplit][row] = m[r];
      MLl[ksplit][row] = l[r];
    }
  }
  __syncthreads();
  float wmul[4];
  #pragma unroll
  for (int r = 0; r < 4; ++r) {
    const int row = qsub * 16 + quad * 4 + r;
    const float m0 = MLm[0][row], m1 = MLm[1][row];
    const float M = fmaxf(m0, m1);
    const float L = MLl[0][row] * exp2f(m0 - M) + MLl[1][row] * exp2f(m1 - M);
    wmul[r] = exp2f(m[r] - M) / L;
  }
  if (ksplit == 0) {
    #pragma unroll
    for (int dt = 0; dt < 16; ++dt)
      #pragma unroll
      for (int r = 0; r < 4; ++r)
        Oacc[(qsub * 16 + quad * 4 + r) * 258 + dt * 16 + ln] = o[dt][r] * wmul[r];
  }
  __syncthreads();
  if (ksplit == 1) {
    #pragma unroll
    for (int dt = 0; dt < 16; ++dt)
      #pragma unroll
      for (int r = 0; r < 4; ++r)
        Oacc[(qsub * 16 + quad * 4 + r) * 258 + dt * 16 + ln] += o[dt][r] * wmul[r];
  }
  __syncthreads();

  // ---- coalesced fp32 write-out: 32 rows x 256 cols ----
  #pragma unroll
  for (int i = 0; i < 8; ++i) {
    const int idx = i * 256 + tid;
    const int row = idx >> 6;
    const int c4 = (idx & 63) << 2;
    floatx4 v = *(const floatx4 *)&Oacc[row * 258 + c4];
    *(floatx4 *)&Out[(size_t)(b * LSEQ + qt * 32 + row) * HID + c4] = v;
  }
}

// ---------------------------------------------------------------------------
extern "C" void kernel_launch(void *const *d_in, const int *in_sizes, int n_in,
                              void *d_out, int out_size, void *d_ws, size_t ws_size,
                              hipStream_t stream) {
  const float *X = (const float *)d_in[0];
  const float *Wq = (const float *)d_in[1];
  const float *Wk = (const float *)d_in[2];
  const float *Wv = (const float *)d_in[3];
  // d_in[4] = lengths (unused by reference)

  __bf16 *ws = (__bf16 *)d_ws;
  const size_t PLANE = (size_t)NTOK * HID;  // 4,194,304 elements
  __bf16 *Qh = ws;
  __bf16 *Ql = Qh + PLANE;
  __bf16 *Kh = Ql + PLANE;
  __bf16 *Kl = Kh + PLANE;
  __bf16 *Vt = Kl + PLANE;                   // [B][256][4096]
  __bf16 *Wht = Vt + PLANE;                  // [3][256][256]
  __bf16 *Wlt = Wht + 3 * HID * HID;

  wsplit<<<3, 256, 0, stream>>>(Wq, Wk, Wv, Wht, Wlt);
  qkv_proj<<<dim3(256, 4), 256, 0, stream>>>(X, Wht, Wlt, Qh, Ql, Kh, Kl, Vt);
  attn<<<512, 256, 0, stream>>>(Qh, Ql, Kh, Kl, Vt, (float *)d_out);
}

// Round 3
// 353.114 us; speedup vs baseline: 2.4296x; 2.4296x over previous
//
#include <hip/hip_runtime.h>

// SelfAttention: B=4, L=4096, H=256, fp32 in/out.
// Round 3: LDS-staged flash attention (r1 structure) + split-K x2 across blocks
// (grid 512 -> 2 blocks/CU, barrier drains overlap) + register-prefetch pipeline
// (next tile's global loads issued before compute, hidden under MFMA phase).
// Partials merged by a small 4th kernel. qkv_proj now stages W tiles in LDS
// (r2's direct-global W frags were 16-segment L2 gathers -> latency-bound).
// Precision: split-bf16 3-product QK (logits O(1e4), near-tie rows need fp32-
// accurate logits; measured absmax 0.25 @ threshold 1.01), plain-bf16 PV,
// bf16 unnormalized O-partials (adds <=0.05).

typedef __bf16 bf16x8 __attribute__((ext_vector_type(8)));
typedef __bf16 bf16x4 __attribute__((ext_vector_type(4)));
typedef float floatx4 __attribute__((ext_vector_type(4)));

#define MFMA16(a, b, c) __builtin_amdgcn_mfma_f32_16x16x32_bf16(a, b, c, 0, 0, 0)

#define HID 256
#define LSEQ 4096
#define NB 4
#define NTOK (NB * LSEQ)             // 16384
#define PLANE ((size_t)NTOK * HID)   // 4,194,304 elements
#define QSCALE 0.09016844005556021f  // log2(e)/16 ; folded into Q so softmax uses exp2

__device__ __forceinline__ void split_bf16(float v, __bf16 &h, __bf16 &l) {
  h = (__bf16)v;
  l = (__bf16)(v - (float)h);
}

// ---------------------------------------------------------------------------
// Kernel 1: transpose + hi/lo-split the three weight matrices.
// ---------------------------------------------------------------------------
__global__ __launch_bounds__(256) void wsplit(const float *__restrict__ Wq,
                                              const float *__restrict__ Wk,
                                              const float *__restrict__ Wv,
                                              __bf16 *__restrict__ Wht,
                                              __bf16 *__restrict__ Wlt) {
  __shared__ float tile[32][256];  // 32 KB
  const int wsel = blockIdx.x;
  const float *W = (wsel == 0) ? Wq : (wsel == 1) ? Wk : Wv;
  __bf16 *oh = Wht + wsel * HID * HID;
  __bf16 *ol = Wlt + wsel * HID * HID;
  const int t = threadIdx.x;
  for (int hb = 0; hb < 8; ++hb) {
    __syncthreads();
    #pragma unroll
    for (int p = 0; p < 8; ++p) {
      int r = p * 4 + (t >> 6);
      int c = (t & 63) * 4;
      *(floatx4 *)&tile[r][c] = *(const floatx4 *)&W[(hb * 32 + r) * HID + c];
    }
    __syncthreads();
    #pragma unroll
    for (int q = 0; q < 4; ++q) {
      int n = q * 64 + (t >> 2);
      int hs = (t & 3) * 8;
      bf16x8 hh, ll;
      #pragma unroll
      for (int i = 0; i < 8; ++i) {
        float v = tile[hs + i][n];
        __bf16 h, l;
        split_bf16(v, h, l);
        hh[i] = h; ll[i] = l;
      }
      *(bf16x8 *)&oh[n * HID + hb * 32 + hs] = hh;
      *(bf16x8 *)&ol[n * HID + hb * 32 + hs] = ll;
    }
  }
}

// ---------------------------------------------------------------------------
// Kernel 2: QKV projection. W tiles staged in LDS (one w-phase at a time),
// A-frags (X, hi/lo split) built once in registers and reused across phases.
// grid = (256 m-tiles, 4 n-tiles), 256 thr. LDS 67.6 KB -> 2 blocks/CU.
// ---------------------------------------------------------------------------
__global__ __launch_bounds__(256, 2) void qkv_proj(const float *__restrict__ X,
                                                   const __bf16 *__restrict__ Wht,
                                                   const __bf16 *__restrict__ Wlt,
                                                   __bf16 *__restrict__ Qh, __bf16 *__restrict__ Ql,
                                                   __bf16 *__restrict__ Kh, __bf16 *__restrict__ Kl,
                                                   __bf16 *__restrict__ Vt) {
  __shared__ __bf16 WhS[64 * 264];
  __shared__ __bf16 WlS[64 * 264];
  const int mtile = blockIdx.x;
  const int col0 = blockIdx.y * 64;
  const int tid = threadIdx.x;
  const int w4 = tid >> 6;
  const int lane = tid & 63;
  const int quad = lane >> 4;
  const int ln = lane & 15;
  const int arow = mtile * 64 + w4 * 16 + ln;

  // A-frags once: 8 k-chunks of X row, hi/lo split.
  bf16x8 ah[8], al[8];
  #pragma unroll
  for (int kc = 0; kc < 8; ++kc) {
    const float *xp = X + (size_t)arow * HID + kc * 32 + quad * 8;
    floatx4 x0 = *(const floatx4 *)xp;
    floatx4 x1 = *(const floatx4 *)(xp + 4);
    #pragma unroll
    for (int j = 0; j < 4; ++j) {
      __bf16 h, l;
      split_bf16(x0[j], h, l); ah[kc][j] = h; al[kc][j] = l;
      split_bf16(x1[j], h, l); ah[kc][4 + j] = h; al[kc][4 + j] = l;
    }
  }

  const int srow = tid >> 2;   // staging: row 0..63
  const int sseg = tid & 3;    // 4 x 16B segs per 64B run

  for (int w = 0; w < 3; ++w) {
    __syncthreads();
    const size_t wbase = (size_t)w * HID * HID + (size_t)(col0 + srow) * HID;
    #pragma unroll
    for (int j = 0; j < 8; ++j) {
      const int el = j * 32 + sseg * 8;
      *(bf16x8 *)&WhS[srow * 264 + el] = *(const bf16x8 *)&Wht[wbase + el];
      *(bf16x8 *)&WlS[srow * 264 + el] = *(const bf16x8 *)&Wlt[wbase + el];
    }
    __syncthreads();

    floatx4 acc[4] = {};
    #pragma unroll
    for (int kc = 0; kc < 8; ++kc) {
      #pragma unroll
      for (int nt = 0; nt < 4; ++nt) {
        const int a = (nt * 16 + ln) * 264 + kc * 32 + quad * 8;
        bf16x8 bh = *(const bf16x8 *)&WhS[a];
        bf16x8 bl = *(const bf16x8 *)&WlS[a];
        acc[nt] = MFMA16(ah[kc], bh, acc[nt]);
        acc[nt] = MFMA16(ah[kc], bl, acc[nt]);
        acc[nt] = MFMA16(al[kc], bh, acc[nt]);
      }
    }

    // Epilogue. C/D: col = lane&15, row = quad*4 + reg.
    if (w == 2) {
      const int bb = mtile >> 6;
      const int l0 = (mtile & 63) * 64 + w4 * 16 + quad * 4;
      #pragma unroll
      for (int nt = 0; nt < 4; ++nt) {
        const int d = col0 + nt * 16 + ln;
        bf16x4 pk;
        #pragma unroll
        for (int r = 0; r < 4; ++r) pk[r] = (__bf16)acc[nt][r];
        *(bf16x4 *)&Vt[(size_t)(bb * HID + d) * LSEQ + l0] = pk;
      }
    } else {
      __bf16 *H = (w == 0) ? Qh : Kh;
      __bf16 *L = (w == 0) ? Ql : Kl;
      const float sc = (w == 0) ? QSCALE : 1.0f;
      #pragma unroll
      for (int nt = 0; nt < 4; ++nt) {
        #pragma unroll
        for (int r = 0; r < 4; ++r) {
          float v = acc[nt][r] * sc;
          __bf16 h, l;
          split_bf16(v, h, l);
          const int orow = mtile * 64 + w4 * 16 + quad * 4 + r;
          const int ocol = col0 + nt * 16 + ln;
          H[orow * HID + ocol] = h;
          L[orow * HID + ocol] = l;
        }
      }
    }
  }
}

// ---------------------------------------------------------------------------
// Kernel 3: flash attention, split-K x2, LDS-staged, reg-prefetch pipeline.
// grid = 512 (qt = bx>>1 over 256 q-tiles of 64 rows, ks = bx&1 key half),
// 256 thr = 4 waves x 16 q-rows. 64 iters of 32 keys. LDS 59.4 KB -> 2 blk/CU.
// Emits unnormalized bf16 O-partials + fp32 m/l; merged by kernel 4.
// ---------------------------------------------------------------------------
__global__ __launch_bounds__(256, 2) void attn(const __bf16 *__restrict__ QhG,
                                               const __bf16 *__restrict__ QlG,
                                               const __bf16 *__restrict__ KhG,
                                               const __bf16 *__restrict__ KlG,
                                               const __bf16 *__restrict__ VtG,
                                               __bf16 *__restrict__ Op,
                                               float *__restrict__ Mp,
                                               float *__restrict__ Lp) {
  __shared__ __bf16 KhS[32 * 264];
  __shared__ __bf16 KlS[32 * 264];
  __shared__ __bf16 VtS[256 * 40];
  __shared__ __bf16 PsS[4 * 16 * 40];

  const int bx = blockIdx.x;
  const int ks = bx & 1;
  const int qt = bx >> 1;          // 0..255
  const int b = qt >> 6;
  const int qtl = qt & 63;
  const int tid = threadIdx.x;
  const int w4 = tid >> 6;
  const int lane = tid & 63;
  const int quad = lane >> 4;
  const int ln = lane & 15;
  const int kbase = ks * 2048;

  // Q frags (hi+lo) for this wave's 16 q-rows.
  const int qtok = b * LSEQ + qtl * 64 + w4 * 16 + ln;
  bf16x8 qh[8], ql[8];
  #pragma unroll
  for (int kc = 0; kc < 8; ++kc) {
    const size_t off = (size_t)qtok * HID + kc * 32 + quad * 8;
    qh[kc] = *(const bf16x8 *)&QhG[off];
    ql[kc] = *(const bf16x8 *)&QlG[off];
  }

  // Staging thread mapping (coalesced): K rows by tid>>5, 16B segs by tid&31;
  // V row = tid, 4x16B chunks xor-swizzled by tid&3.
  const int skey = tid >> 5;
  const int scol = (tid & 31) * 8;
  const int ssw = tid & 3;
  const __bf16 *vgbase = VtG + (size_t)(b * HID + tid) * LSEQ + kbase;

  bf16x8 gkh[4], gkl[4], gkv[4];  // prefetch registers
  {
    #pragma unroll
    for (int p = 0; p < 4; ++p) {
      const size_t g = (size_t)(b * LSEQ + kbase + p * 8 + skey) * HID + scol;
      gkh[p] = *(const bf16x8 *)&KhG[g];
      gkl[p] = *(const bf16x8 *)&KlG[g];
    }
    #pragma unroll
    for (int c = 0; c < 4; ++c) gkv[c] = *(const bf16x8 *)&vgbase[c * 8];
  }

  float m[4] = {-1e30f, -1e30f, -1e30f, -1e30f};
  float l[4] = {0.f, 0.f, 0.f, 0.f};
  floatx4 o[16] = {};

  for (int kt = 0; kt < 64; ++kt) {
    __syncthreads();  // all waves done reading previous tile
    // ---- regs -> LDS ----
    #pragma unroll
    for (int p = 0; p < 4; ++p) {
      const int a = (p * 8 + skey) * 264 + scol;
      *(bf16x8 *)&KhS[a] = gkh[p];
      *(bf16x8 *)&KlS[a] = gkl[p];
    }
    #pragma unroll
    for (int c = 0; c < 4; ++c)
      *(bf16x8 *)&VtS[tid * 40 + ((c ^ ssw) << 3)] = gkv[c];
    __syncthreads();  // tile ready

    // ---- prefetch next tile (lands during compute below) ----
    if (kt < 63) {
      #pragma unroll
      for (int p = 0; p < 4; ++p) {
        const size_t g = (size_t)(b * LSEQ + kbase + (kt + 1) * 32 + p * 8 + skey) * HID + scol;
        gkh[p] = *(const bf16x8 *)&KhG[g];
        gkl[p] = *(const bf16x8 *)&KlG[g];
      }
      const __bf16 *vg = vgbase + (kt + 1) * 32;
      #pragma unroll
      for (int c = 0; c < 4; ++c) gkv[c] = *(const bf16x8 *)&vg[c * 8];
    }

    // ---- S = Q K^T (3-product split) ----
    floatx4 s[2] = {};
    #pragma unroll
    for (int nt = 0; nt < 2; ++nt) {
      #pragma unroll
      for (int kc = 0; kc < 8; ++kc) {
        const int a = (nt * 16 + ln) * 264 + kc * 32 + quad * 8;
        bf16x8 bh = *(const bf16x8 *)&KhS[a];
        bf16x8 bl = *(const bf16x8 *)&KlS[a];
        s[nt] = MFMA16(qh[kc], bh, s[nt]);
        s[nt] = MFMA16(qh[kc], bl, s[nt]);
        s[nt] = MFMA16(ql[kc], bh, s[nt]);
      }
    }

    // ---- online softmax (base-2) ----
    float alpha[4];
    #pragma unroll
    for (int r = 0; r < 4; ++r) {
      float tmax = fmaxf(s[0][r], s[1][r]);
      #pragma unroll
      for (int d = 1; d < 16; d <<= 1) tmax = fmaxf(tmax, __shfl_xor(tmax, d));
      const float mn = fmaxf(m[r], tmax);
      const float al = exp2f(m[r] - mn);
      const float p0 = exp2f(s[0][r] - mn);
      const float p1 = exp2f(s[1][r] - mn);
      s[0][r] = p0; s[1][r] = p1;
      float rs = p0 + p1;
      #pragma unroll
      for (int d = 1; d < 16; d <<= 1) rs += __shfl_xor(rs, d);
      l[r] = l[r] * al + rs;
      m[r] = mn;
      alpha[r] = al;
    }
    #pragma unroll
    for (int dt = 0; dt < 16; ++dt) {
      o[dt][0] *= alpha[0]; o[dt][1] *= alpha[1];
      o[dt][2] *= alpha[2]; o[dt][3] *= alpha[3];
    }

    // ---- P round-trip (per-wave region, same-wave: no barrier) ----
    __bf16 *ps = PsS + w4 * 16 * 40;
    #pragma unroll
    for (int nt = 0; nt < 2; ++nt)
      #pragma unroll
      for (int r = 0; r < 4; ++r)
        ps[(quad * 4 + r) * 40 + nt * 16 + ln] = (__bf16)s[nt][r];
    const bf16x8 pa = *(const bf16x8 *)&ps[ln * 40 + quad * 8];

    // ---- O += P V ----
    #pragma unroll
    for (int dt = 0; dt < 16; ++dt) {
      const int cs = (quad ^ (ln & 3)) << 3;
      bf16x8 vb = *(const bf16x8 *)&VtS[(dt * 16 + ln) * 40 + cs];
      o[dt] = MFMA16(pa, vb, o[dt]);
    }
  }

  // ---- partials: unnormalized O (bf16) + m/l (fp32) ----
  const int rowbase = b * LSEQ + qtl * 64 + w4 * 16 + quad * 4;
  #pragma unroll
  for (int dt = 0; dt < 16; ++dt)
    #pragma unroll
    for (int r = 0; r < 4; ++r)
      Op[(size_t)ks * PLANE + (size_t)(rowbase + r) * HID + dt * 16 + ln] = (__bf16)o[dt][r];
  if (ln == 0) {
    #pragma unroll
    for (int r = 0; r < 4; ++r) {
      Mp[ks * NTOK + rowbase + r] = m[r];
      Lp[ks * NTOK + rowbase + r] = l[r];
    }
  }
}

// ---------------------------------------------------------------------------
// Kernel 4: split-K merge. grid 4096 x 256 thr; thread = 4 cols of one row.
// ---------------------------------------------------------------------------
__global__ __launch_bounds__(256) void merge(const __bf16 *__restrict__ Op,
                                             const float *__restrict__ Mp,
                                             const float *__restrict__ Lp,
                                             float *__restrict__ Out) {
  const int row = blockIdx.x * 4 + (threadIdx.x >> 6);
  const int c = (threadIdx.x & 63) * 4;
  const float m0 = Mp[row], m1 = Mp[NTOK + row];
  const float l0 = Lp[row], l1 = Lp[NTOK + row];
  const float M = fmaxf(m0, m1);
  const float e0 = exp2f(m0 - M), e1 = exp2f(m1 - M);
  const float invL = 1.0f / (l0 * e0 + l1 * e1);
  const float w0 = e0 * invL, w1 = e1 * invL;
  bf16x4 a = *(const bf16x4 *)&Op[(size_t)row * HID + c];
  bf16x4 b4 = *(const bf16x4 *)&Op[PLANE + (size_t)row * HID + c];
  floatx4 out;
  #pragma unroll
  for (int i = 0; i < 4; ++i) out[i] = w0 * (float)a[i] + w1 * (float)b4[i];
  *(floatx4 *)&Out[(size_t)row * HID + c] = out;
}

// ---------------------------------------------------------------------------
extern "C" void kernel_launch(void *const *d_in, const int *in_sizes, int n_in,
                              void *d_out, int out_size, void *d_ws, size_t ws_size,
                              hipStream_t stream) {
  const float *X = (const float *)d_in[0];
  const float *Wq = (const float *)d_in[1];
  const float *Wk = (const float *)d_in[2];
  const float *Wv = (const float *)d_in[3];
  // d_in[4] = lengths (unused by reference)

  // Workspace (bf16 elements unless noted). ~59.8 MB total.
  __bf16 *ws = (__bf16 *)d_ws;
  __bf16 *Qh = ws;
  __bf16 *Ql = Qh + PLANE;
  __bf16 *Kh = Ql + PLANE;
  __bf16 *Kl = Kh + PLANE;
  __bf16 *Vt = Kl + PLANE;                   // [B][256][4096]
  __bf16 *Wht = Vt + PLANE;                  // [3][256][256]
  __bf16 *Wlt = Wht + 3 * HID * HID;
  __bf16 *Op = Wlt + 3 * HID * HID;          // [2][16384][256] unnormalized
  float *Mp = (float *)(Op + 2 * PLANE);     // [2][16384]
  float *Lp = Mp + 2 * NTOK;                 // [2][16384]

  wsplit<<<3, 256, 0, stream>>>(Wq, Wk, Wv, Wht, Wlt);
  qkv_proj<<<dim3(256, 4), 256, 0, stream>>>(X, Wht, Wlt, Qh, Ql, Kh, Kl, Vt);
  attn<<<512, 256, 0, stream>>>(Qh, Ql, Kh, Kl, Vt, Op, Mp, Lp);
  merge<<<NTOK / 4, 256, 0, stream>>>(Op, Mp, Lp, (float *)d_out);
}

// Round 4
// 308.090 us; speedup vs baseline: 2.7846x; 1.1461x over previous
//
#include <hip/hip_runtime.h>

// SelfAttention: B=4, L=4096, H=256, fp32 in/out.
// Round 4: conflict-free LDS everywhere + V off the LDS pipe.
//  - K hi/lo stored FRAGMENT-LINEAR in global (qkv epilogue does LDS transpose);
//    attn stages it with a linear memcpy (coalesced loads -> consecutive LDS
//    writes) and reads frags as wave-contiguous 1KB ds_read_b128 -> conflict-free.
//  - K LDS double-buffered, ONE barrier per iter (dbuf spacing covers hazards).
//  - V stored fragment-linear in global and read directly (no LDS): all waves
//    read identical coalesced 1KB frags -> L1-served, parallel to LDS pipe.
//  - qkv W-tile LDS uses xor swizzle (chunk^(row&7), stride 256).
// Precision: split-bf16 3-product QK (fp32-accurate logits; logits O(1e4) with
// near-tie rows), plain-bf16 PV, bf16 O-partials. Measured absmax 0.25 @ 1.01.

typedef __bf16 bf16x8 __attribute__((ext_vector_type(8)));
typedef __bf16 bf16x4 __attribute__((ext_vector_type(4)));
typedef float floatx4 __attribute__((ext_vector_type(4)));

#define MFMA16(a, b, c) __builtin_amdgcn_mfma_f32_16x16x32_bf16(a, b, c, 0, 0, 0)

#define HID 256
#define LSEQ 4096
#define NB 4
#define NTOK (NB * LSEQ)             // 16384
#define PLANE ((size_t)NTOK * HID)   // 4,194,304 elements
#define QSCALE 0.09016844005556021f  // log2(e)/16 ; softmax uses exp2

// Fragment-linear layouts (32-key tiles, T = global tile = tok>>5, 512 tiles):
//  Kf[T][hi/lo][nt(2)][kc(8)][lane(64)][j(8)] : tile stride 16384 el (hi 0..8191, lo +8192)
//    element = K(hi/lo)[key = T*32 + nt*16 + (lane&15)][h = kc*32 + (lane>>4)*8 + j]
//  Vf[T][dt(16)][lane(64)][j(8)] : tile stride 8192 el
//    element = V[key = T*32 + (lane>>4)*8 + j][d = dt*16 + (lane&15)]

__device__ __forceinline__ void split_bf16(float v, __bf16 &h, __bf16 &l) {
  h = (__bf16)v;
  l = (__bf16)(v - (float)h);
}

// ---------------------------------------------------------------------------
// Kernel 1: transpose + hi/lo-split weights -> Wht/Wlt [3][n][h] row-major.
// ---------------------------------------------------------------------------
__global__ __launch_bounds__(256) void wsplit(const float *__restrict__ Wq,
                                              const float *__restrict__ Wk,
                                              const float *__restrict__ Wv,
                                              __bf16 *__restrict__ Wht,
                                              __bf16 *__restrict__ Wlt) {
  __shared__ float tile[32][256];
  const int wsel = blockIdx.x;
  const float *W = (wsel == 0) ? Wq : (wsel == 1) ? Wk : Wv;
  __bf16 *oh = Wht + wsel * HID * HID;
  __bf16 *ol = Wlt + wsel * HID * HID;
  const int t = threadIdx.x;
  for (int hb = 0; hb < 8; ++hb) {
    __syncthreads();
    #pragma unroll
    for (int p = 0; p < 8; ++p) {
      int r = p * 4 + (t >> 6);
      int c = (t & 63) * 4;
      *(floatx4 *)&tile[r][c] = *(const floatx4 *)&W[(hb * 32 + r) * HID + c];
    }
    __syncthreads();
    #pragma unroll
    for (int q = 0; q < 4; ++q) {
      int n = q * 64 + (t >> 2);
      int hs = (t & 3) * 8;
      bf16x8 hh, ll;
      #pragma unroll
      for (int i = 0; i < 8; ++i) {
        float v = tile[hs + i][n];
        __bf16 h, l;
        split_bf16(v, h, l);
        hh[i] = h; ll[i] = l;
      }
      *(bf16x8 *)&oh[n * HID + hb * 32 + hs] = hh;
      *(bf16x8 *)&ol[n * HID + hb * 32 + hs] = ll;
    }
  }
}

// ---------------------------------------------------------------------------
// Kernel 2: QKV projection. W tiles in LDS (xor-swizzled, stride 256); A-frags
// in regs. Epilogues: Q row-major hi/lo; K,V -> fragment-linear global via LDS
// transpose (scratch aliases the W tile region, bracketed by barriers).
// grid = (256 m-tiles of 64 tokens, 4 col-tiles of 64), 256 thr.
// ---------------------------------------------------------------------------
__global__ __launch_bounds__(256, 2) void qkv_proj(const float *__restrict__ X,
                                                   const __bf16 *__restrict__ Wht,
                                                   const __bf16 *__restrict__ Wlt,
                                                   __bf16 *__restrict__ Qh, __bf16 *__restrict__ Ql,
                                                   __bf16 *__restrict__ Kf,
                                                   __bf16 *__restrict__ Vf) {
  __shared__ __bf16 WhS[64 * 256];
  __shared__ __bf16 WlS[64 * 256];
  __bf16 *Th = WhS;            // 64 x 72 scratch (aliases WhS, post-barrier)
  __bf16 *Tl = WhS + 64 * 72;  // 64 x 72
  __bf16 *Tv = WhS;            // 64 x 72

  const int mtile = blockIdx.x;
  const int col0 = blockIdx.y * 64;
  const int tid = threadIdx.x;
  const int w4 = tid >> 6;
  const int lane = tid & 63;
  const int quad = lane >> 4;
  const int ln = lane & 15;
  const int arow = mtile * 64 + w4 * 16 + ln;

  // A-frags once: 8 k-chunks of X row, hi/lo split.
  bf16x8 ah[8], al[8];
  #pragma unroll
  for (int kc = 0; kc < 8; ++kc) {
    const float *xp = X + (size_t)arow * HID + kc * 32 + quad * 8;
    floatx4 x0 = *(const floatx4 *)xp;
    floatx4 x1 = *(const floatx4 *)(xp + 4);
    #pragma unroll
    for (int j = 0; j < 4; ++j) {
      __bf16 h, l;
      split_bf16(x0[j], h, l); ah[kc][j] = h; al[kc][j] = l;
      split_bf16(x1[j], h, l); ah[kc][4 + j] = h; al[kc][4 + j] = l;
    }
  }

  const int srow = tid >> 2;   // staging row 0..63
  const int sseg = tid & 3;

  for (int w = 0; w < 3; ++w) {
    __syncthreads();  // W region free (prev MFMA reads / scratch reads done)
    const size_t wbase = (size_t)w * HID * HID + (size_t)(col0 + srow) * HID;
    #pragma unroll
    for (int j = 0; j < 8; ++j) {
      const int chunk = j * 4 + sseg;
      const int dst = srow * 256 + ((chunk ^ (srow & 7)) << 3);
      *(bf16x8 *)&WhS[dst] = *(const bf16x8 *)&Wht[wbase + chunk * 8];
      *(bf16x8 *)&WlS[dst] = *(const bf16x8 *)&Wlt[wbase + chunk * 8];
    }
    __syncthreads();

    floatx4 acc[4] = {};
    #pragma unroll
    for (int kc = 0; kc < 8; ++kc) {
      #pragma unroll
      for (int nt = 0; nt < 4; ++nt) {
        const int a = (nt * 16 + ln) * 256 + (((kc * 4 + quad) ^ (ln & 7)) << 3);
        bf16x8 bh = *(const bf16x8 *)&WhS[a];
        bf16x8 bl = *(const bf16x8 *)&WlS[a];
        acc[nt] = MFMA16(ah[kc], bh, acc[nt]);
        acc[nt] = MFMA16(ah[kc], bl, acc[nt]);
        acc[nt] = MFMA16(al[kc], bh, acc[nt]);
      }
    }

    // Epilogues. C/D: col = lane&15, row = quad*4 + reg.
    if (w == 0) {
      #pragma unroll
      for (int nt = 0; nt < 4; ++nt) {
        #pragma unroll
        for (int r = 0; r < 4; ++r) {
          float v = acc[nt][r] * QSCALE;
          __bf16 h, l;
          split_bf16(v, h, l);
          const int orow = mtile * 64 + w4 * 16 + quad * 4 + r;
          const int ocol = col0 + nt * 16 + ln;
          Qh[(size_t)orow * HID + ocol] = h;
          Ql[(size_t)orow * HID + ocol] = l;
        }
      }
    } else if (w == 1) {
      __syncthreads();  // all MFMA reads of WhS done before scratch clobber
      #pragma unroll
      for (int nt = 0; nt < 4; ++nt) {
        #pragma unroll
        for (int r = 0; r < 4; ++r) {
          __bf16 h, l;
          split_bf16(acc[nt][r], h, l);
          const int tok_l = w4 * 16 + quad * 4 + r;
          const int h_l = nt * 16 + ln;
          Th[tok_l * 72 + h_l] = h;
          Tl[tok_l * 72 + h_l] = l;
        }
      }
      __syncthreads();
      #pragma unroll
      for (int i = 0; i < 2; ++i) {
        const int c = i * 256 + tid;           // 512 chunks
        const int lane_f = c & 63;
        const int ntf = (c >> 6) & 1;
        const int kcL = (c >> 7) & 1;
        const int t2 = (c >> 8) & 1;
        const int qf = lane_f >> 4;
        const int lnf = lane_f & 15;
        const int tok_l = t2 * 32 + ntf * 16 + lnf;
        bf16x8 vh = *(const bf16x8 *)&Th[tok_l * 72 + kcL * 32 + qf * 8];
        bf16x8 vl = *(const bf16x8 *)&Tl[tok_l * 72 + kcL * 32 + qf * 8];
        const int T = mtile * 2 + t2;
        const int kc = (col0 >> 5) + kcL;
        const size_t dst = (size_t)T * 16384 + ((ntf * 8 + kc) * 64 + lane_f) * 8;
        *(bf16x8 *)&Kf[dst] = vh;
        *(bf16x8 *)&Kf[dst + 8192] = vl;
      }
    } else {
      __syncthreads();
      #pragma unroll
      for (int nt = 0; nt < 4; ++nt) {
        #pragma unroll
        for (int r = 0; r < 4; ++r) {
          const int tok_l = w4 * 16 + quad * 4 + r;
          const int d_l = nt * 16 + ln;
          Tv[d_l * 72 + tok_l] = (__bf16)acc[nt][r];
        }
      }
      __syncthreads();
      #pragma unroll
      for (int i = 0; i < 2; ++i) {
        const int c = i * 256 + tid;           // 512 chunks
        const int lane_f = c & 63;
        const int dtL = (c >> 6) & 3;
        const int t2 = (c >> 8) & 1;
        const int qf = lane_f >> 4;
        const int lnf = lane_f & 15;
        const int d_l = dtL * 16 + lnf;
        bf16x8 v = *(const bf16x8 *)&Tv[d_l * 72 + t2 * 32 + qf * 8];
        const int T = mtile * 2 + t2;
        const int dt = (col0 >> 4) + dtL;
        *(bf16x8 *)&Vf[(size_t)(T * 16 + dt) * 512 + lane_f * 8] = v;
      }
    }
  }
}

// ---------------------------------------------------------------------------
// Kernel 3: flash attention. grid = 512 (qt = bx>>1, ks = bx&1), 256 thr.
// K: frag-linear global -> linear LDS memcpy, double-buffered, ONE barrier/iter.
// V: frag-linear global, read direct (2 batches of 8 frags). P: per-wave LDS
// round-trip. Emits unnormalized bf16 O-partials + fp32 m/l.
// ---------------------------------------------------------------------------
__global__ __launch_bounds__(256, 2) void attn(const __bf16 *__restrict__ QhG,
                                               const __bf16 *__restrict__ QlG,
                                               const __bf16 *__restrict__ Kf,
                                               const __bf16 *__restrict__ Vf,
                                               __bf16 *__restrict__ Op,
                                               float *__restrict__ Mp,
                                               float *__restrict__ Lp) {
  __shared__ __bf16 KS[2][16384];       // dbuf: [hi 8192 | lo 8192] per buffer
  __shared__ __bf16 PsS[4 * 16 * 40];

  const int bx = blockIdx.x;
  const int ks = bx & 1;
  const int qt = bx >> 1;
  const int b = qt >> 6;
  const int qtl = qt & 63;
  const int tid = threadIdx.x;
  const int w4 = tid >> 6;
  const int lane = tid & 63;
  const int quad = lane >> 4;
  const int ln = lane & 15;
  const int T0 = b * 128 + ks * 64;     // first global 32-key tile

  // Q frags (hi+lo), once.
  const int qtok = b * LSEQ + qtl * 64 + w4 * 16 + ln;
  bf16x8 qh[8], ql[8];
  #pragma unroll
  for (int kc = 0; kc < 8; ++kc) {
    const size_t off = (size_t)qtok * HID + kc * 32 + quad * 8;
    qh[kc] = *(const bf16x8 *)&QhG[off];
    ql[kc] = *(const bf16x8 *)&QlG[off];
  }

  // Preload tile 0 staging regs (linear memcpy chunks: 8 x 16B per thread).
  bf16x8 gk[8];
  {
    const __bf16 *src = Kf + (size_t)T0 * 16384 + tid * 8;
    #pragma unroll
    for (int i = 0; i < 8; ++i) gk[i] = *(const bf16x8 *)&src[i * 2048];
  }

  float m[4] = {-1e30f, -1e30f, -1e30f, -1e30f};
  float l[4] = {0.f, 0.f, 0.f, 0.f};
  floatx4 o[16] = {};

  for (int kt = 0; kt < 64; ++kt) {
    __bf16 *buf = KS[kt & 1];
    // regs -> LDS (linear, conflict-free). Readers of this buffer finished in
    // iter kt-2; the barrier in iter kt-1 separates them from these writes.
    #pragma unroll
    for (int i = 0; i < 8; ++i)
      *(bf16x8 *)&buf[i * 2048 + tid * 8] = gk[i];
    __syncthreads();  // the only barrier per iter

    // prefetch next K tile into regs (hidden under this iter's compute)
    if (kt < 63) {
      const __bf16 *src = Kf + (size_t)(T0 + kt + 1) * 16384 + tid * 8;
      #pragma unroll
      for (int i = 0; i < 8; ++i) gk[i] = *(const bf16x8 *)&src[i * 2048];
    }

    // V frags batch 1 (direct global, frag-linear, used in PV at iter end)
    const __bf16 *vsrc = Vf + (size_t)(T0 + kt) * 8192 + lane * 8;
    bf16x8 vb0[8];
    #pragma unroll
    for (int dt = 0; dt < 8; ++dt) vb0[dt] = *(const bf16x8 *)&vsrc[dt * 512];

    // ---- S = Q K^T (3-product split), frags = contiguous 1KB ds_read ----
    floatx4 s[2] = {};
    #pragma unroll
    for (int nt = 0; nt < 2; ++nt) {
      #pragma unroll
      for (int kc = 0; kc < 8; ++kc) {
        const __bf16 *kp = buf + (nt * 8 + kc) * 512 + lane * 8;
        bf16x8 bh = *(const bf16x8 *)kp;
        bf16x8 bl = *(const bf16x8 *)(kp + 8192);
        s[nt] = MFMA16(qh[kc], bh, s[nt]);
        s[nt] = MFMA16(qh[kc], bl, s[nt]);
        s[nt] = MFMA16(ql[kc], bh, s[nt]);
      }
    }

    // V frags batch 2 (latency covered by softmax + P round-trip)
    bf16x8 vb1[8];
    #pragma unroll
    for (int dt = 0; dt < 8; ++dt) vb1[dt] = *(const bf16x8 *)&vsrc[(8 + dt) * 512];

    // ---- online softmax (base-2) ----
    float alpha[4];
    #pragma unroll
    for (int r = 0; r < 4; ++r) {
      float tmax = fmaxf(s[0][r], s[1][r]);
      #pragma unroll
      for (int d = 1; d < 16; d <<= 1) tmax = fmaxf(tmax, __shfl_xor(tmax, d));
      const float mn = fmaxf(m[r], tmax);
      const float al = exp2f(m[r] - mn);
      const float p0 = exp2f(s[0][r] - mn);
      const float p1 = exp2f(s[1][r] - mn);
      s[0][r] = p0; s[1][r] = p1;
      float rs = p0 + p1;
      #pragma unroll
      for (int d = 1; d < 16; d <<= 1) rs += __shfl_xor(rs, d);
      l[r] = l[r] * al + rs;
      m[r] = mn;
      alpha[r] = al;
    }
    #pragma unroll
    for (int dt = 0; dt < 16; ++dt) {
      o[dt][0] *= alpha[0]; o[dt][1] *= alpha[1];
      o[dt][2] *= alpha[2]; o[dt][3] *= alpha[3];
    }

    // ---- P round-trip (per-wave region, same-wave: no barrier) ----
    __bf16 *ps = PsS + w4 * 16 * 40;
    #pragma unroll
    for (int nt = 0; nt < 2; ++nt)
      #pragma unroll
      for (int r = 0; r < 4; ++r)
        ps[(quad * 4 + r) * 40 + nt * 16 + ln] = (__bf16)s[nt][r];
    const bf16x8 pa = *(const bf16x8 *)&ps[ln * 40 + quad * 8];

    // ---- O += P V ----
    #pragma unroll
    for (int dt = 0; dt < 8; ++dt) o[dt] = MFMA16(pa, vb0[dt], o[dt]);
    #pragma unroll
    for (int dt = 0; dt < 8; ++dt) o[8 + dt] = MFMA16(pa, vb1[dt], o[8 + dt]);
  }

  // ---- partials: unnormalized O (bf16) + m/l (fp32) ----
  const int rowbase = b * LSEQ + qtl * 64 + w4 * 16 + quad * 4;
  #pragma unroll
  for (int dt = 0; dt < 16; ++dt)
    #pragma unroll
    for (int r = 0; r < 4; ++r)
      Op[(size_t)ks * PLANE + (size_t)(rowbase + r) * HID + dt * 16 + ln] = (__bf16)o[dt][r];
  if (ln == 0) {
    #pragma unroll
    for (int r = 0; r < 4; ++r) {
      Mp[ks * NTOK + rowbase + r] = m[r];
      Lp[ks * NTOK + rowbase + r] = l[r];
    }
  }
}

// ---------------------------------------------------------------------------
// Kernel 4: split-K merge. grid 4096 x 256 thr; thread = 4 cols of one row.
// ---------------------------------------------------------------------------
__global__ __launch_bounds__(256) void merge(const __bf16 *__restrict__ Op,
                                             const float *__restrict__ Mp,
                                             const float *__restrict__ Lp,
                                             float *__restrict__ Out) {
  const int row = blockIdx.x * 4 + (threadIdx.x >> 6);
  const int c = (threadIdx.x & 63) * 4;
  const float m0 = Mp[row], m1 = Mp[NTOK + row];
  const float l0 = Lp[row], l1 = Lp[NTOK + row];
  const float M = fmaxf(m0, m1);
  const float e0 = exp2f(m0 - M), e1 = exp2f(m1 - M);
  const float invL = 1.0f / (l0 * e0 + l1 * e1);
  const float w0 = e0 * invL, w1 = e1 * invL;
  bf16x4 a = *(const bf16x4 *)&Op[(size_t)row * HID + c];
  bf16x4 b4 = *(const bf16x4 *)&Op[PLANE + (size_t)row * HID + c];
  floatx4 out;
  #pragma unroll
  for (int i = 0; i < 4; ++i) out[i] = w0 * (float)a[i] + w1 * (float)b4[i];
  *(floatx4 *)&Out[(size_t)row * HID + c] = out;
}

// ---------------------------------------------------------------------------
extern "C" void kernel_launch(void *const *d_in, const int *in_sizes, int n_in,
                              void *d_out, int out_size, void *d_ws, size_t ws_size,
                              hipStream_t stream) {
  const float *X = (const float *)d_in[0];
  const float *Wq = (const float *)d_in[1];
  const float *Wk = (const float *)d_in[2];
  const float *Wv = (const float *)d_in[3];
  // d_in[4] = lengths (unused by reference)

  // Workspace (bf16 elements unless noted). ~57.5 MB total.
  __bf16 *ws = (__bf16 *)d_ws;
  __bf16 *Qh = ws;                           // [16384][256] row-major
  __bf16 *Ql = Qh + PLANE;
  __bf16 *Kf = Ql + PLANE;                   // frag-linear, 2*PLANE (hi+lo per tile)
  __bf16 *Vf = Kf + 2 * PLANE;               // frag-linear, PLANE
  __bf16 *Wht = Vf + PLANE;                  // [3][256][256]
  __bf16 *Wlt = Wht + 3 * HID * HID;
  __bf16 *Op = Wlt + 3 * HID * HID;          // [2][16384][256] unnormalized
  float *Mp = (float *)(Op + 2 * PLANE);     // [2][16384]
  float *Lp = Mp + 2 * NTOK;                 // [2][16384]

  wsplit<<<3, 256, 0, stream>>>(Wq, Wk, Wv, Wht, Wlt);
  qkv_proj<<<dim3(256, 4), 256, 0, stream>>>(X, Wht, Wlt, Qh, Ql, Kf, Vf);
  attn<<<512, 256, 0, stream>>>(Qh, Ql, Kf, Vf, Op, Mp, Lp);
  merge<<<NTOK / 4, 256, 0, stream>>>(Op, Mp, Lp, (float *)d_out);
}